// Round 1
// baseline (1412.174 us; speedup 1.0000x reference)
//
#include <hip/hip_runtime.h>
#include <math.h>

#define BS   32
#define IC   64
#define OC   64
#define HH   128
#define WW   128
#define BANK 256
#define ADDR 64
#define WELEM (OC*IC*9)   // 36864 weight elems per bank entry

// ---------------- kernel 1: sel_w = softmax(w_addr @ aspace^T) --------------
__global__ __launch_bounds__(BANK) void k_selw(const float* __restrict__ w_addr,
                                               const float* __restrict__ aspace,
                                               float* __restrict__ sel_w) {
    int b = blockIdx.x;
    int n = threadIdx.x;
    const float* wa = w_addr + b * ADDR;
    const float* as = aspace + n * ADDR;
    float dot = 0.f;
#pragma unroll
    for (int k = 0; k < ADDR; ++k) dot = fmaf(wa[k], as[k], dot);

    __shared__ float red[BANK];
    red[n] = dot; __syncthreads();
    for (int s = BANK / 2; s > 0; s >>= 1) {
        if (n < s) red[n] = fmaxf(red[n], red[n + s]);
        __syncthreads();
    }
    float m = red[0]; __syncthreads();
    float e = expf(dot - m);
    red[n] = e; __syncthreads();
    for (int s = BANK / 2; s > 0; s >>= 1) {
        if (n < s) red[n] += red[n + s];
        __syncthreads();
    }
    sel_w[b * BANK + n] = e / red[0];
}

// ---------------- kernel 2: bias[b][o] = softmax(b_addr@aspace^T) @ b_bank --
__global__ __launch_bounds__(BANK) void k_bias(const float* __restrict__ b_addr,
                                               const float* __restrict__ aspace,
                                               const float* __restrict__ b_bank,
                                               float* __restrict__ bias) {
    int bo = blockIdx.x;      // b*OC + o
    int n  = threadIdx.x;
    const float* ba = b_addr + (size_t)bo * ADDR;
    const float* as = aspace + n * ADDR;
    float dot = 0.f;
#pragma unroll
    for (int k = 0; k < ADDR; ++k) dot = fmaf(ba[k], as[k], dot);

    __shared__ float red[BANK];
    red[n] = dot; __syncthreads();
    for (int s = BANK / 2; s > 0; s >>= 1) {
        if (n < s) red[n] = fmaxf(red[n], red[n + s]);
        __syncthreads();
    }
    float m = red[0]; __syncthreads();
    float e = expf(dot - m);
    red[n] = e; __syncthreads();
    for (int s = BANK / 2; s > 0; s >>= 1) {
        if (n < s) red[n] += red[n + s];
        __syncthreads();
    }
    float denom = red[0]; __syncthreads();
    red[n] = e * b_bank[n]; __syncthreads();
    for (int s = BANK / 2; s > 0; s >>= 1) {
        if (n < s) red[n] += red[n + s];
        __syncthreads();
    }
    if (n == 0) bias[bo] = red[0] / denom;
}

// ---------------- kernel 3: wmix[b][j] = sum_n sel_w[b][n]*w_bank[n][j] -----
__global__ __launch_bounds__(256) void k_wmix(const float* __restrict__ sel_w,
                                              const float* __restrict__ w_bank,
                                              float* __restrict__ wmix) {
    int j = blockIdx.x * 256 + threadIdx.x;   // 0..WELEM-1
    float acc[BS];
#pragma unroll
    for (int b = 0; b < BS; ++b) acc[b] = 0.f;
    for (int n = 0; n < BANK; ++n) {
        float wv = w_bank[(size_t)n * WELEM + j];
#pragma unroll
        for (int b = 0; b < BS; ++b)
            acc[b] = fmaf(sel_w[b * BANK + n], wv, acc[b]);
    }
#pragma unroll
    for (int b = 0; b < BS; ++b)
        wmix[(size_t)b * WELEM + j] = acc[b];
}

// ---------------- kernel 4: per-sample 3x3 conv + bias ----------------------
// block: 256 threads, handles (b, 8 out-channels, 32x32 spatial tile)
// LDS: input chunk of 8 ic with 1-px halo, row stride 36 floats (144B, 16B-aligned,
// shifts 4 words/row -> even bank spread on b128 reads)
#define OCG 8
#define TH  32
#define TW  32
#define ICC 8
#define LRS 36

__global__ __launch_bounds__(256) void k_conv(const float* __restrict__ x,
                                              const float* __restrict__ wmix,
                                              const float* __restrict__ bias,
                                              float* __restrict__ out) {
    __shared__ float s_in[ICC * 34 * LRS];   // 9792 floats
    __shared__ float s_w[ICC * 9 * OCG];     // 576 floats, [ic][tap][oc]

    int bid  = blockIdx.x;
    int tile = bid & 15;
    int tx   = (tile & 3) * TW;
    int ty   = (tile >> 2) * TH;
    int oc0  = ((bid >> 4) & 7) * OCG;
    int b    = bid >> 7;

    int tid = threadIdx.x;
    int r   = tid >> 3;          // 0..31 tile row
    int cb  = (tid & 7) * 4;     // 0..28 col base (4 px per thread)

    float acc[OCG][4];
#pragma unroll
    for (int o = 0; o < OCG; ++o)
#pragma unroll
        for (int p = 0; p < 4; ++p) acc[o][p] = 0.f;

    for (int ic0 = 0; ic0 < IC; ic0 += ICC) {
        // stage input tile (with halo, zero-padded at borders)
        for (int i = tid; i < ICC * 34 * 34; i += 256) {
            int c   = i / 1156;
            int rem = i - c * 1156;
            int rr  = rem / 34;
            int col = rem - rr * 34;
            int gy = ty + rr - 1, gx = tx + col - 1;
            float v = 0.f;
            if ((unsigned)gy < HH && (unsigned)gx < WW)
                v = x[(((size_t)b * IC + ic0 + c) * HH + gy) * WW + gx];
            s_in[(c * 34 + rr) * LRS + col] = v;
        }
        // stage weights for this (b, oc-group, ic chunk): layout [ic][tap][oc]
        for (int i = tid; i < ICC * 9 * OCG; i += 256) {
            int oc  = i & 7;
            int t   = i >> 3;        // ic*9 + tap
            int tap = t % 9;
            int ic  = t / 9;
            s_w[i] = wmix[(((size_t)b * OC + oc0 + oc) * IC + ic0 + ic) * 9 + tap];
        }
        __syncthreads();

#pragma unroll
        for (int ic = 0; ic < ICC; ++ic) {
#pragma unroll
            for (int ky = 0; ky < 3; ++ky) {
                const float* rp = &s_in[(ic * 34 + r + ky) * LRS + cb];
                float win[6];
#pragma unroll
                for (int q = 0; q < 6; ++q) win[q] = rp[q];
#pragma unroll
                for (int kx = 0; kx < 3; ++kx) {
                    const float* wp = &s_w[(ic * 9 + ky * 3 + kx) * OCG];
#pragma unroll
                    for (int o = 0; o < OCG; ++o) {
                        float wt = wp[o];
                        acc[o][0] = fmaf(win[kx + 0], wt, acc[o][0]);
                        acc[o][1] = fmaf(win[kx + 1], wt, acc[o][1]);
                        acc[o][2] = fmaf(win[kx + 2], wt, acc[o][2]);
                        acc[o][3] = fmaf(win[kx + 3], wt, acc[o][3]);
                    }
                }
            }
        }
        __syncthreads();
    }

    int oy = ty + r;
    int ox = tx + cb;
#pragma unroll
    for (int o = 0; o < OCG; ++o) {
        float bv = bias[b * OC + oc0 + o];
        float4 o4 = make_float4(acc[o][0] + bv, acc[o][1] + bv,
                                acc[o][2] + bv, acc[o][3] + bv);
        *(float4*)&out[(((size_t)b * OC + oc0 + o) * HH + oy) * WW + ox] = o4;
    }
}

// ---------------------------------------------------------------------------
extern "C" void kernel_launch(void* const* d_in, const int* in_sizes, int n_in,
                              void* d_out, int out_size, void* d_ws, size_t ws_size,
                              hipStream_t stream) {
    const float* x      = (const float*)d_in[0];
    const float* w_addr = (const float*)d_in[1];
    const float* b_addr = (const float*)d_in[2];
    const float* w_bank = (const float*)d_in[3];
    const float* b_bank = (const float*)d_in[4];
    const float* aspace = (const float*)d_in[5];
    // d_in[6]=s, d_in[7]=p: always 1 in this problem (stride 1, pad 1)
    float* out = (float*)d_out;

    float* ws     = (float*)d_ws;
    float* sel_w  = ws;              // 32*256      = 8192 floats
    float* bias   = ws + 8192;       // 32*64       = 2048 floats
    float* wmix   = ws + 16384;      // 32*36864    = 1179648 floats

    k_selw<<<BS, BANK, 0, stream>>>(w_addr, aspace, sel_w);
    k_bias<<<BS * OC, BANK, 0, stream>>>(b_addr, aspace, b_bank, bias);
    k_wmix<<<WELEM / 256, 256, 0, stream>>>(sel_w, w_bank, wmix);
    k_conv<<<BS * 8 * 16, 256, 0, stream>>>(x, wmix, bias, out);
}

// Round 2
// 269.572 us; speedup vs baseline: 5.2386x; 5.2386x over previous
//
#include <hip/hip_runtime.h>
#include <hip/hip_bf16.h>
#include <math.h>

#define BS   32
#define IC   64
#define OC   64
#define HH   128
#define WW   128
#define BANK 256
#define ADDR 64
#define WELEM (OC*IC*9)

typedef short short8 __attribute__((ext_vector_type(8)));
typedef float f32x16 __attribute__((ext_vector_type(16)));

__device__ __forceinline__ short f2bf(float f) {
    unsigned u = __builtin_bit_cast(unsigned, f);
    unsigned r = (u + 0x7FFFu + ((u >> 16) & 1u)) >> 16;
    return (short)r;
}

// ---------------- kernel 1: sel_w = softmax(w_addr @ aspace^T) --------------
__global__ __launch_bounds__(BANK) void k_selw(const float* __restrict__ w_addr,
                                               const float* __restrict__ aspace,
                                               float* __restrict__ sel_w) {
    int b = blockIdx.x;
    int n = threadIdx.x;
    const float* wa = w_addr + b * ADDR;
    const float* as = aspace + n * ADDR;
    float dot = 0.f;
#pragma unroll
    for (int k = 0; k < ADDR; ++k) dot = fmaf(wa[k], as[k], dot);

    __shared__ float red[BANK];
    red[n] = dot; __syncthreads();
    for (int s = BANK / 2; s > 0; s >>= 1) {
        if (n < s) red[n] = fmaxf(red[n], red[n + s]);
        __syncthreads();
    }
    float m = red[0]; __syncthreads();
    float e = expf(dot - m);
    red[n] = e; __syncthreads();
    for (int s = BANK / 2; s > 0; s >>= 1) {
        if (n < s) red[n] += red[n + s];
        __syncthreads();
    }
    sel_w[b * BANK + n] = e / red[0];
}

// ---------------- kernel 2: bias[b][o] = softmax(b_addr@aspace^T) @ b_bank --
__global__ __launch_bounds__(BANK) void k_bias(const float* __restrict__ b_addr,
                                               const float* __restrict__ aspace,
                                               const float* __restrict__ b_bank,
                                               float* __restrict__ bias) {
    int bo = blockIdx.x;
    int n  = threadIdx.x;
    const float* ba = b_addr + (size_t)bo * ADDR;
    const float* as = aspace + n * ADDR;
    float dot = 0.f;
#pragma unroll
    for (int k = 0; k < ADDR; ++k) dot = fmaf(ba[k], as[k], dot);

    __shared__ float red[BANK];
    red[n] = dot; __syncthreads();
    for (int s = BANK / 2; s > 0; s >>= 1) {
        if (n < s) red[n] = fmaxf(red[n], red[n + s]);
        __syncthreads();
    }
    float m = red[0]; __syncthreads();
    float e = expf(dot - m);
    red[n] = e; __syncthreads();
    for (int s = BANK / 2; s > 0; s >>= 1) {
        if (n < s) red[n] += red[n + s];
        __syncthreads();
    }
    float denom = red[0]; __syncthreads();
    red[n] = e * b_bank[n]; __syncthreads();
    for (int s = BANK / 2; s > 0; s >>= 1) {
        if (n < s) red[n] += red[n + s];
        __syncthreads();
    }
    if (n == 0) bias[bo] = red[0] / denom;
}

// ---------------- kernel 3: weight mix -> bf16, MFMA-fragment layout --------
// out layout: wmb[b][tap(9)][icg(8)][oc(64)][ic8(8)]  (bf16)
__global__ __launch_bounds__(256) void k_wmix(const float* __restrict__ sel_w,
                                              const float* __restrict__ w_bank,
                                              __hip_bfloat16* __restrict__ wmb) {
    int j = blockIdx.x * 256 + threadIdx.x;   // 0..WELEM-1, = (o*IC+i)*9 + tap
    int o   = j / 576;
    int rem = j - o * 576;
    int i   = rem / 9;
    int tap = rem - i * 9;

    float acc[BS];
#pragma unroll
    for (int b = 0; b < BS; ++b) acc[b] = 0.f;
    for (int n = 0; n < BANK; ++n) {
        float wv = w_bank[(size_t)n * WELEM + j];
#pragma unroll
        for (int b = 0; b < BS; ++b)
            acc[b] = fmaf(sel_w[b * BANK + n], wv, acc[b]);
    }
    size_t base = ((size_t)tap * 8 + (i >> 3)) * 64 * 8 + (size_t)o * 8 + (i & 7);
#pragma unroll
    for (int b = 0; b < BS; ++b) {
        short v = f2bf(acc[b]);
        wmb[(size_t)b * (9 * 8 * 64 * 8) + base] = *reinterpret_cast<__hip_bfloat16*>(&v);
    }
}

// ---------------- kernel 4: x NCHW f32 -> NHWC bf16 -------------------------
// xbf[b][y][x][ic]; block = (b,y), 256 threads
__global__ __launch_bounds__(256) void k_tr(const float* __restrict__ x,
                                            __hip_bfloat16* __restrict__ xbf) {
    int bid = blockIdx.x;              // b*128 + y
    int b = bid >> 7, y = bid & 127;
    int tid = threadIdx.x;
    const float* xb = x + ((size_t)b * IC * HH + y) * WW;
    __hip_bfloat16* ob = xbf + (size_t)bid * WW * IC;
    int px   = tid & 127;
    int icg0 = tid >> 7;               // 0..1
#pragma unroll
    for (int u = 0; u < 4; ++u) {
        int icg = icg0 + u * 2;        // 0..7
        short8 v;
#pragma unroll
        for (int e = 0; e < 8; ++e) {
            float f = xb[(size_t)(icg * 8 + e) * HH * WW + px];
            v[e] = f2bf(f);
        }
        *(short8*)(ob + (size_t)px * IC + icg * 8) = v;
    }
}

// ---------------- kernel 5: implicit-GEMM conv, 32x32x16 bf16 MFMA ----------
// block: 512 thr / 8 waves; covers sample b, 8 output rows, all 64 oc.
// wave w: output row y0+w, 64 oc (2 m-tiles) x 128 px (4 n-tiles).
// K = ic, 2 chunks of 32; per chunk 9 taps x 2 K16-steps.
#define ROWS 8
#define XR   10

__global__ __launch_bounds__(512, 2) void k_conv(
    const __hip_bfloat16* __restrict__ xbf,   // [32][128][128][64]
    const __hip_bfloat16* __restrict__ wmb,   // [32][9][8][64][8]
    const float* __restrict__ bias,           // [32][64]
    float* __restrict__ out)                  // [32][64][128][128]
{
    __shared__ short s_x[XR * 4 * 132 * 8];   // 84480 B
    __shared__ short s_w[9 * 4 * 64 * 8];     // 36864 B
    __shared__ float s_bias[OC];

    int bid   = blockIdx.x;
    int strip = bid & 15;
    int b     = bid >> 4;
    int y0    = strip * ROWS;
    int tid   = threadIdx.x;
    int w     = tid >> 6;        // wave 0..7
    int lane  = tid & 63;
    int h     = lane >> 5;       // k-group half
    int ln    = lane & 31;

    if (tid < OC) s_bias[tid] = bias[b * OC + tid];

    f32x16 acc[2][4];
#pragma unroll
    for (int mt = 0; mt < 2; ++mt)
#pragma unroll
        for (int nt = 0; nt < 4; ++nt) acc[mt][nt] = (f32x16)0.0f;

    const short8* sx8 = (const short8*)s_x;
    const short8* sw8 = (const short8*)s_w;

    for (int chunk = 0; chunk < 2; ++chunk) {
        // ---- stage x chunk: rows y0-1..y0+8, cols -1..128, 32 ic ----
        const __hip_bfloat16* xb = xbf + (size_t)b * HH * WW * IC + chunk * 32;
        for (int i = tid; i < XR * 4 * 130; i += 512) {
            int ky = i / 520;
            int r  = i - ky * 520;
            int g  = r / 130;
            int c  = r - g * 130;
            int gy = y0 - 1 + ky;
            int gx = c - 1;
            short8 v = {0, 0, 0, 0, 0, 0, 0, 0};
            if ((unsigned)gy < (unsigned)HH && (unsigned)gx < (unsigned)WW)
                v = *(const short8*)(xb + ((size_t)gy * WW + gx) * IC + g * 8);
            *(short8*)&s_x[((ky * 4 + g) * 132 + c) * 8] = v;
        }
        // ---- stage w chunk: [9][4][64][8] <- wmb[b][tap][chunk*4+g][oc][8] --
        const __hip_bfloat16* wb = wmb + (size_t)b * (9 * 8 * 64 * 8) + chunk * 4 * 64 * 8;
        for (int i = tid; i < 9 * 4 * 64; i += 512) {
            int tap = i >> 8;
            int r   = i & 255;
            int g   = r >> 6;
            int oc  = r & 63;
            short8 v = *(const short8*)(wb + ((size_t)(tap * 8 + g) * 64 + oc) * 8);
            *(short8*)&s_w[i * 8] = v;
        }
        __syncthreads();

        // ---- compute: 9 taps x 2 K16-steps, 8 MFMA each ----
#pragma unroll
        for (int ky = 0; ky < 3; ++ky) {
#pragma unroll
            for (int kx = 0; kx < 3; ++kx) {
#pragma unroll
                for (int ks = 0; ks < 2; ++ks) {
                    int gq = ks * 2 + h;
                    int tap = ky * 3 + kx;
                    short8 a0 = sw8[(tap * 4 + gq) * 64 + ln];
                    short8 a1 = sw8[(tap * 4 + gq) * 64 + 32 + ln];
#pragma unroll
                    for (int nt = 0; nt < 4; ++nt) {
                        short8 bf = sx8[((w + ky) * 4 + gq) * 132 + nt * 32 + ln + kx];
                        acc[0][nt] = __builtin_amdgcn_mfma_f32_32x32x16_bf16(a0, bf, acc[0][nt], 0, 0, 0);
                        acc[1][nt] = __builtin_amdgcn_mfma_f32_32x32x16_bf16(a1, bf, acc[1][nt], 0, 0, 0);
                    }
                }
            }
        }
        __syncthreads();
    }

    // ---- epilogue: C/D layout col=lane&31, row=(r&3)+8*(r>>2)+4*h ----
    int y = y0 + w;
    float* ob = out + (size_t)b * OC * HH * WW;
#pragma unroll
    for (int mt = 0; mt < 2; ++mt) {
#pragma unroll
        for (int nt = 0; nt < 4; ++nt) {
#pragma unroll
            for (int r = 0; r < 16; ++r) {
                int oc = mt * 32 + (r & 3) + 8 * (r >> 2) + 4 * h;
                int px = nt * 32 + ln;
                ob[((size_t)oc * HH + y) * WW + px] = acc[mt][nt][r] + s_bias[oc];
            }
        }
    }
}

// ---------------------------------------------------------------------------
extern "C" void kernel_launch(void* const* d_in, const int* in_sizes, int n_in,
                              void* d_out, int out_size, void* d_ws, size_t ws_size,
                              hipStream_t stream) {
    const float* x      = (const float*)d_in[0];
    const float* w_addr = (const float*)d_in[1];
    const float* b_addr = (const float*)d_in[2];
    const float* w_bank = (const float*)d_in[3];
    const float* b_bank = (const float*)d_in[4];
    const float* aspace = (const float*)d_in[5];
    float* out = (float*)d_out;

    char* ws = (char*)d_ws;
    float*          sel_w = (float*)ws;                         // 32768 B
    float*          bias  = (float*)(ws + 32768);               //  8192 B
    __hip_bfloat16* wmb   = (__hip_bfloat16*)(ws + 40960);      // 2359296 B
    __hip_bfloat16* xbf   = (__hip_bfloat16*)(ws + 40960 + 2359296); // 64 MB

    k_selw<<<BS, BANK, 0, stream>>>(w_addr, aspace, sel_w);
    k_bias<<<BS * OC, BANK, 0, stream>>>(b_addr, aspace, b_bank, bias);
    k_wmix<<<WELEM / 256, 256, 0, stream>>>(sel_w, w_bank, wmb);
    k_tr<<<BS * HH, 256, 0, stream>>>(x, xbf);
    k_conv<<<BS * (HH / ROWS), 512, 0, stream>>>(xbf, wmb, bias, out);
}

// Round 3
// 172.605 us; speedup vs baseline: 8.1816x; 1.5618x over previous
//
#include <hip/hip_runtime.h>
#include <hip/hip_bf16.h>
#include <math.h>

#define BS   32
#define IC   64
#define OC   64
#define HH   128
#define WW   128
#define BANK 256
#define ADDR 64
#define WELEM (OC*IC*9)

typedef short short8 __attribute__((ext_vector_type(8)));
typedef float f32x16 __attribute__((ext_vector_type(16)));

__device__ __forceinline__ short f2bf(float f) {
    unsigned u = __builtin_bit_cast(unsigned, f);
    unsigned r = (u + 0x7FFFu + ((u >> 16) & 1u)) >> 16;
    return (short)r;
}

// ---------------- kernel 1: sel_w = softmax(w_addr @ aspace^T) --------------
__global__ __launch_bounds__(BANK) void k_selw(const float* __restrict__ w_addr,
                                               const float* __restrict__ aspace,
                                               float* __restrict__ sel_w) {
    int b = blockIdx.x;
    int n = threadIdx.x;
    const float* wa = w_addr + b * ADDR;
    const float* as = aspace + n * ADDR;
    float dot = 0.f;
#pragma unroll
    for (int k = 0; k < ADDR; ++k) dot = fmaf(wa[k], as[k], dot);

    __shared__ float red[BANK];
    red[n] = dot; __syncthreads();
    for (int s = BANK / 2; s > 0; s >>= 1) {
        if (n < s) red[n] = fmaxf(red[n], red[n + s]);
        __syncthreads();
    }
    float m = red[0]; __syncthreads();
    float e = expf(dot - m);
    red[n] = e; __syncthreads();
    for (int s = BANK / 2; s > 0; s >>= 1) {
        if (n < s) red[n] += red[n + s];
        __syncthreads();
    }
    sel_w[b * BANK + n] = e / red[0];
}

// ---------------- kernel 2: bias[b][o] = softmax(b_addr@aspace^T) @ b_bank --
__global__ __launch_bounds__(BANK) void k_bias(const float* __restrict__ b_addr,
                                               const float* __restrict__ aspace,
                                               const float* __restrict__ b_bank,
                                               float* __restrict__ bias) {
    int bo = blockIdx.x;
    int n  = threadIdx.x;
    const float* ba = b_addr + (size_t)bo * ADDR;
    const float* as = aspace + n * ADDR;
    float dot = 0.f;
#pragma unroll
    for (int k = 0; k < ADDR; ++k) dot = fmaf(ba[k], as[k], dot);

    __shared__ float red[BANK];
    red[n] = dot; __syncthreads();
    for (int s = BANK / 2; s > 0; s >>= 1) {
        if (n < s) red[n] = fmaxf(red[n], red[n + s]);
        __syncthreads();
    }
    float m = red[0]; __syncthreads();
    float e = expf(dot - m);
    red[n] = e; __syncthreads();
    for (int s = BANK / 2; s > 0; s >>= 1) {
        if (n < s) red[n] += red[n + s];
        __syncthreads();
    }
    float denom = red[0]; __syncthreads();
    red[n] = e * b_bank[n]; __syncthreads();
    for (int s = BANK / 2; s > 0; s >>= 1) {
        if (n < s) red[n] += red[n + s];
        __syncthreads();
    }
    if (n == 0) bias[bo] = red[0] / denom;
}

// ---------------- kernel 3: weight mix -> bf16, MFMA-fragment layout --------
// Split-K: 576 blocks x 256 thr; wave = one 64-wide n-chunk (wave-uniform ->
// sel_w scalarizes to s_loads). Thread: 64 coalesced wv loads + 2048 v_fmac.
// LDS reduce over 4 chunks, then bf16 scatter into
// wmb[b][tap(9)][icg(8)][oc(64)][ic8(8)].
__global__ __launch_bounds__(256) void k_wmix(const float* __restrict__ sel_w,
                                              const float* __restrict__ w_bank,
                                              __hip_bfloat16* __restrict__ wmb) {
    __shared__ float s_red[4 * 32 * 64];   // [chunk][b][jl] = 32 KB

    int tid = threadIdx.x;
    int jl  = tid & 63;
    int c   = tid >> 6;                    // wave id = n-chunk
    int jb  = blockIdx.x * 64 + jl;

    int n0 = __builtin_amdgcn_readfirstlane(c * 64);
    const float* selp = sel_w + n0;        // uniform base -> s_load operands

    float wv[64];
#pragma unroll
    for (int n = 0; n < 64; ++n)
        wv[n] = w_bank[(size_t)(n0 + n) * WELEM + jb];

    float acc[BS];
#pragma unroll
    for (int b = 0; b < BS; ++b) acc[b] = 0.f;
#pragma unroll
    for (int b = 0; b < BS; ++b)
#pragma unroll
        for (int n = 0; n < 64; ++n)
            acc[b] = fmaf(selp[b * BANK + n], wv[n], acc[b]);

#pragma unroll
    for (int b = 0; b < BS; ++b)
        s_red[(c * 32 + b) * 64 + jl] = acc[b];   // lanes->consecutive banks
    __syncthreads();

    // each thread: one jl2, 8 consecutive b's
    int B0  = (tid * 8) & 31;
    int jl2 = (tid * 8) >> 5;
    int j   = blockIdx.x * 64 + jl2;
    int o   = j / 576;
    int rem = j - o * 576;
    int i   = rem / 9;
    int tap = rem - i * 9;
    size_t base = ((size_t)tap * 8 + (i >> 3)) * 512 + (size_t)o * 8 + (i & 7);
#pragma unroll
    for (int u = 0; u < 8; ++u) {
        int b = B0 + u;
        float v = s_red[(0 * 32 + b) * 64 + jl2] + s_red[(1 * 32 + b) * 64 + jl2]
                + s_red[(2 * 32 + b) * 64 + jl2] + s_red[(3 * 32 + b) * 64 + jl2];
        short sv = f2bf(v);
        wmb[(size_t)b * (9 * 8 * 64 * 8) + base] = *reinterpret_cast<__hip_bfloat16*>(&sv);
    }
}

// ---------------- kernel 4: x NCHW f32 -> NHWC bf16 -------------------------
// lane = icg fastest -> short8 stores contiguous 128B per 8 lanes.
__global__ __launch_bounds__(256) void k_tr(const float* __restrict__ x,
                                            __hip_bfloat16* __restrict__ xbf) {
    int bid = blockIdx.x;              // b*128 + y
    int b = bid >> 7, y = bid & 127;
    int tid = threadIdx.x;
    const float* xb = x + ((size_t)b * IC * HH + y) * WW;
    __hip_bfloat16* ob = xbf + (size_t)bid * WW * IC;
    int icg = tid & 7;                 // 0..7
    int px0 = (tid >> 3) * 4;          // 0..124

    float4 v[8];
#pragma unroll
    for (int e = 0; e < 8; ++e)
        v[e] = *(const float4*)&xb[(size_t)(icg * 8 + e) * HH * WW + px0];
#pragma unroll
    for (int p = 0; p < 4; ++p) {
        short8 s;
#pragma unroll
        for (int e = 0; e < 8; ++e)
            s[e] = f2bf(((const float*)&v[e])[p]);
        *(short8*)(ob + (size_t)(px0 + p) * IC + icg * 8) = s;
    }
}

// ---------------- kernel 5: implicit-GEMM conv, 32x32x16 bf16 MFMA ----------
#define ROWS 8
#define XR   10

__global__ __launch_bounds__(512, 2) void k_conv(
    const __hip_bfloat16* __restrict__ xbf,   // [32][128][128][64]
    const __hip_bfloat16* __restrict__ wmb,   // [32][9][8][64][8]
    const float* __restrict__ bias,           // [32][64]
    float* __restrict__ out)                  // [32][64][128][128]
{
    __shared__ short s_x[XR * 4 * 132 * 8];   // 84480 B
    __shared__ short s_w[9 * 4 * 64 * 8];     // 36864 B
    __shared__ float s_bias[OC];

    int bid   = blockIdx.x;
    int strip = bid & 15;
    int b     = bid >> 4;
    int y0    = strip * ROWS;
    int tid   = threadIdx.x;
    int w     = tid >> 6;        // wave 0..7
    int lane  = tid & 63;
    int h     = lane >> 5;       // k-group half
    int ln    = lane & 31;

    if (tid < OC) s_bias[tid] = bias[b * OC + tid];

    f32x16 acc[2][4];
#pragma unroll
    for (int mt = 0; mt < 2; ++mt)
#pragma unroll
        for (int nt = 0; nt < 4; ++nt) acc[mt][nt] = (f32x16)0.0f;

    const short8* sx8 = (const short8*)s_x;
    const short8* sw8 = (const short8*)s_w;

    for (int chunk = 0; chunk < 2; ++chunk) {
        const __hip_bfloat16* xb = xbf + (size_t)b * HH * WW * IC + chunk * 32;
        for (int i = tid; i < XR * 4 * 130; i += 512) {
            int ky = i / 520;
            int r  = i - ky * 520;
            int g  = r / 130;
            int c  = r - g * 130;
            int gy = y0 - 1 + ky;
            int gx = c - 1;
            short8 v = {0, 0, 0, 0, 0, 0, 0, 0};
            if ((unsigned)gy < (unsigned)HH && (unsigned)gx < (unsigned)WW)
                v = *(const short8*)(xb + ((size_t)gy * WW + gx) * IC + g * 8);
            *(short8*)&s_x[((ky * 4 + g) * 132 + c) * 8] = v;
        }
        const __hip_bfloat16* wb = wmb + (size_t)b * (9 * 8 * 64 * 8) + chunk * 4 * 64 * 8;
        for (int i = tid; i < 9 * 4 * 64; i += 512) {
            int tap = i >> 8;
            int r   = i & 255;
            int g   = r >> 6;
            int oc  = r & 63;
            short8 v = *(const short8*)(wb + ((size_t)(tap * 8 + g) * 64 + oc) * 8);
            *(short8*)&s_w[i * 8] = v;
        }
        __syncthreads();

#pragma unroll
        for (int ky = 0; ky < 3; ++ky) {
#pragma unroll
            for (int kx = 0; kx < 3; ++kx) {
#pragma unroll
                for (int ks = 0; ks < 2; ++ks) {
                    int gq = ks * 2 + h;
                    int tap = ky * 3 + kx;
                    short8 a0 = sw8[(tap * 4 + gq) * 64 + ln];
                    short8 a1 = sw8[(tap * 4 + gq) * 64 + 32 + ln];
#pragma unroll
                    for (int nt = 0; nt < 4; ++nt) {
                        short8 bf = sx8[((w + ky) * 4 + gq) * 132 + nt * 32 + ln + kx];
                        acc[0][nt] = __builtin_amdgcn_mfma_f32_32x32x16_bf16(a0, bf, acc[0][nt], 0, 0, 0);
                        acc[1][nt] = __builtin_amdgcn_mfma_f32_32x32x16_bf16(a1, bf, acc[1][nt], 0, 0, 0);
                    }
                }
            }
        }
        __syncthreads();
    }

    int y = y0 + w;
    float* ob = out + (size_t)b * OC * HH * WW;
#pragma unroll
    for (int mt = 0; mt < 2; ++mt) {
#pragma unroll
        for (int nt = 0; nt < 4; ++nt) {
#pragma unroll
            for (int r = 0; r < 16; ++r) {
                int oc = mt * 32 + (r & 3) + 8 * (r >> 2) + 4 * h;
                int px = nt * 32 + ln;
                ob[((size_t)oc * HH + y) * WW + px] = acc[mt][nt][r] + s_bias[oc];
            }
        }
    }
}

// ---------------------------------------------------------------------------
extern "C" void kernel_launch(void* const* d_in, const int* in_sizes, int n_in,
                              void* d_out, int out_size, void* d_ws, size_t ws_size,
                              hipStream_t stream) {
    const float* x      = (const float*)d_in[0];
    const float* w_addr = (const float*)d_in[1];
    const float* b_addr = (const float*)d_in[2];
    const float* w_bank = (const float*)d_in[3];
    const float* b_bank = (const float*)d_in[4];
    const float* aspace = (const float*)d_in[5];
    float* out = (float*)d_out;

    char* ws = (char*)d_ws;
    float*          sel_w = (float*)ws;                         // 32768 B
    float*          bias  = (float*)(ws + 32768);               //  8192 B
    __hip_bfloat16* wmb   = (__hip_bfloat16*)(ws + 40960);      // 2359296 B
    __hip_bfloat16* xbf   = (__hip_bfloat16*)(ws + 40960 + 2359296); // 64 MB

    k_selw<<<BS, BANK, 0, stream>>>(w_addr, aspace, sel_w);
    k_bias<<<BS * OC, BANK, 0, stream>>>(b_addr, aspace, b_bank, bias);
    k_wmix<<<WELEM / 64, 256, 0, stream>>>(sel_w, w_bank, wmb);
    k_tr<<<BS * HH, 256, 0, stream>>>(x, xbf);
    k_conv<<<BS * (HH / ROWS), 512, 0, stream>>>(xbf, wmb, bias, out);
}

// Round 4
// 129.493 us; speedup vs baseline: 10.9054x; 1.3329x over previous
//
#include <hip/hip_runtime.h>
#include <hip/hip_bf16.h>
#include <math.h>

#define BS   32
#define IC   64
#define OC   64
#define HH   128
#define WW   128
#define BANK 256
#define ADDR 64
#define WELEM (OC*IC*9)

typedef short short8 __attribute__((ext_vector_type(8)));
typedef float f32x16 __attribute__((ext_vector_type(16)));

__device__ __forceinline__ short f2bf(float f) {
    unsigned u = __builtin_bit_cast(unsigned, f);
    unsigned r = (u + 0x7FFFu + ((u >> 16) & 1u)) >> 16;
    return (short)r;
}

// ---------------- kernel 1: sel_w = softmax(w_addr @ aspace^T) --------------
__global__ __launch_bounds__(BANK) void k_selw(const float* __restrict__ w_addr,
                                               const float* __restrict__ aspace,
                                               float* __restrict__ sel_w) {
    int b = blockIdx.x;
    int n = threadIdx.x;
    const float* wa = w_addr + b * ADDR;
    const float* as = aspace + n * ADDR;
    float dot = 0.f;
#pragma unroll
    for (int k = 0; k < ADDR; ++k) dot = fmaf(wa[k], as[k], dot);

    __shared__ float red[BANK];
    red[n] = dot; __syncthreads();
    for (int s = BANK / 2; s > 0; s >>= 1) {
        if (n < s) red[n] = fmaxf(red[n], red[n + s]);
        __syncthreads();
    }
    float m = red[0]; __syncthreads();
    float e = expf(dot - m);
    red[n] = e; __syncthreads();
    for (int s = BANK / 2; s > 0; s >>= 1) {
        if (n < s) red[n] += red[n + s];
        __syncthreads();
    }
    sel_w[b * BANK + n] = e / red[0];
}

// ---------------- kernel 2: bias[b][o] = softmax(b_addr@aspace^T) @ b_bank --
__global__ __launch_bounds__(BANK) void k_bias(const float* __restrict__ b_addr,
                                               const float* __restrict__ aspace,
                                               const float* __restrict__ b_bank,
                                               float* __restrict__ bias) {
    int bo = blockIdx.x;
    int n  = threadIdx.x;
    const float* ba = b_addr + (size_t)bo * ADDR;
    const float* as = aspace + n * ADDR;
    float dot = 0.f;
#pragma unroll
    for (int k = 0; k < ADDR; ++k) dot = fmaf(ba[k], as[k], dot);

    __shared__ float red[BANK];
    red[n] = dot; __syncthreads();
    for (int s = BANK / 2; s > 0; s >>= 1) {
        if (n < s) red[n] = fmaxf(red[n], red[n + s]);
        __syncthreads();
    }
    float m = red[0]; __syncthreads();
    float e = expf(dot - m);
    red[n] = e; __syncthreads();
    for (int s = BANK / 2; s > 0; s >>= 1) {
        if (n < s) red[n] += red[n + s];
        __syncthreads();
    }
    float denom = red[0]; __syncthreads();
    red[n] = e * b_bank[n]; __syncthreads();
    for (int s = BANK / 2; s > 0; s >>= 1) {
        if (n < s) red[n] += red[n + s];
        __syncthreads();
    }
    if (n == 0) bias[bo] = red[0] / denom;
}

// ---------------- kernel 3: weight mix -> bf16, MFMA-fragment layout --------
// wmb[b][tap(9)][icg(8)][oc(64)][ic8(8)]  (bf16)
__global__ __launch_bounds__(256) void k_wmix(const float* __restrict__ sel_w,
                                              const float* __restrict__ w_bank,
                                              __hip_bfloat16* __restrict__ wmb) {
    __shared__ float s_red[4 * 32 * 64];   // [chunk][b][jl] = 32 KB

    int tid = threadIdx.x;
    int jl  = tid & 63;
    int c   = tid >> 6;
    int jb  = blockIdx.x * 64 + jl;

    int n0 = __builtin_amdgcn_readfirstlane(c * 64);
    const float* selp = sel_w + n0;

    float wv[64];
#pragma unroll
    for (int n = 0; n < 64; ++n)
        wv[n] = w_bank[(size_t)(n0 + n) * WELEM + jb];

    float acc[BS];
#pragma unroll
    for (int b = 0; b < BS; ++b) acc[b] = 0.f;
#pragma unroll
    for (int b = 0; b < BS; ++b)
#pragma unroll
        for (int n = 0; n < 64; ++n)
            acc[b] = fmaf(selp[b * BANK + n], wv[n], acc[b]);

#pragma unroll
    for (int b = 0; b < BS; ++b)
        s_red[(c * 32 + b) * 64 + jl] = acc[b];
    __syncthreads();

    int B0  = (tid * 8) & 31;
    int jl2 = (tid * 8) >> 5;
    int j   = blockIdx.x * 64 + jl2;
    int o   = j / 576;
    int rem = j - o * 576;
    int i   = rem / 9;
    int tap = rem - i * 9;
    size_t base = ((size_t)tap * 8 + (i >> 3)) * 512 + (size_t)o * 8 + (i & 7);
#pragma unroll
    for (int u = 0; u < 8; ++u) {
        int b = B0 + u;
        float v = s_red[(0 * 32 + b) * 64 + jl2] + s_red[(1 * 32 + b) * 64 + jl2]
                + s_red[(2 * 32 + b) * 64 + jl2] + s_red[(3 * 32 + b) * 64 + jl2];
        short sv = f2bf(v);
        wmb[(size_t)b * (9 * 8 * 64 * 8) + base] = *reinterpret_cast<__hip_bfloat16*>(&sv);
    }
}

// ---------------- kernel 4: FUSED implicit-GEMM conv (reads fp32 NCHW) ------
// 1024 blocks = 32 samples x 32 strips of 4 rows; 512 thr / 8 waves.
// wave = (row w&3, oc-half w>>2): 32 oc x 128 px -> 4 acc tiles (64 regs).
// K: 4 chunks of 16 ic. Single-buffer T14 pipeline:
//   [bar; convert+write LDS; issue loads cc+1; bar; MFMA(cc)]
__global__ __launch_bounds__(512) void k_conv(const float* __restrict__ x,
                                              const __hip_bfloat16* __restrict__ wmb,
                                              const float* __restrict__ bias,
                                              float* __restrict__ out) {
    __shared__ short s_x[6 * 2 * 132 * 8];   // 25344 sh = 50688 B... (6 rows,2 icg,132 cols)
    __shared__ short s_w[9 * 2 * 64 * 8];    // 9216 sh = 18432 B
    __shared__ float s_bias[OC];

    int orig    = blockIdx.x;
    int logical = (orig & 7) * 128 + (orig >> 3);   // bijective XCD swizzle (1024%8==0)
    int b     = logical >> 5;
    int strip = logical & 31;
    int y0    = strip * 4;
    int tid   = threadIdx.x;
    int wv    = tid >> 6;
    int lane  = tid & 63;
    int h     = lane >> 5;
    int ln    = lane & 31;
    int wrow  = wv & 3;
    int oc0   = (wv >> 2) * 32;

    if (tid < OC) s_bias[tid] = bias[b * OC + tid];

    const float* xb = x + (size_t)b * IC * HH * WW;
    const __hip_bfloat16* wbb = wmb + (size_t)b * (9 * 8 * 64 * 8);

    // ---- per-thread staging descriptors (chunk-independent) ----
    // x units: u = tid + k*512, u < 1560; unit = (ky<6, g<2, c<130) short8
    int  x_goff[4]; int x_lds[4]; bool x_ok[4]; bool x_val[4];
#pragma unroll
    for (int k = 0; k < 4; ++k) {
        int u = tid + k * 512;
        x_val[k] = (u < 1560);
        int uu = x_val[k] ? u : 0;
        int ky = uu / 260;
        int r  = uu - ky * 260;
        int g  = r / 130;
        int c  = r - g * 130;
        int gy = y0 - 1 + ky;
        int gx = c - 1;
        x_ok[k]   = x_val[k] && ((unsigned)gy < (unsigned)HH) && ((unsigned)gx < (unsigned)WW);
        x_goff[k] = (g * 8) * (HH * WW) + gy * WW + gx;
        x_lds[k]  = ((ky * 2 + g) * 132 + c) * 8;
    }
    // w units: v = tid + k*512, v < 1152; unit = (tap<9, g<2, oc<64) short8
    int w_goff[3]; int w_lds[3]; bool w_val[3];
#pragma unroll
    for (int k = 0; k < 3; ++k) {
        int v = tid + k * 512;
        w_val[k] = (v < 1152);
        int vv = w_val[k] ? v : 0;
        int tap = vv >> 7;
        int r   = vv & 127;
        int g   = r >> 6;
        int oc  = r & 63;
        w_goff[k] = tap * 4096 + g * 512 + oc * 8;   // + cc*1024 per chunk
        w_lds[k]  = ((tap * 2 + g) * 64 + oc) * 8;
    }

    float  xr[4][8];
    short8 wreg[3];

    auto LOADX = [&](int cc) {
#pragma unroll
        for (int k = 0; k < 4; ++k) {
            const float* p = xb + (size_t)cc * 16 * (HH * WW) + x_goff[k];
#pragma unroll
            for (int e = 0; e < 8; ++e)
                xr[k][e] = x_ok[k] ? p[(size_t)e * (HH * WW)] : 0.f;
        }
    };
    auto LOADW = [&](int cc) {
#pragma unroll
        for (int k = 0; k < 3; ++k)
            if (w_val[k])
                wreg[k] = *(const short8*)(wbb + w_goff[k] + cc * 1024);
    };
    auto WRITEX = [&]() {
#pragma unroll
        for (int k = 0; k < 4; ++k) {
            if (x_val[k]) {
                short8 s;
#pragma unroll
                for (int e = 0; e < 8; ++e) s[e] = f2bf(xr[k][e]);
                *(short8*)&s_x[x_lds[k]] = s;
            }
        }
    };
    auto WRITEW = [&]() {
#pragma unroll
        for (int k = 0; k < 3; ++k)
            if (w_val[k]) *(short8*)&s_w[w_lds[k]] = wreg[k];
    };

    f32x16 acc[4];
#pragma unroll
    for (int nt = 0; nt < 4; ++nt) acc[nt] = (f32x16)0.0f;

    const short8* sx8 = (const short8*)s_x;
    const short8* sw8 = (const short8*)s_w;

    LOADX(0); LOADW(0);
    for (int cc = 0; cc < 4; ++cc) {
        if (cc) __syncthreads();           // previous chunk's readers done
        WRITEX();                          // vmcnt drain of loads issued last iter
        WRITEW();
        if (cc < 3) { LOADX(cc + 1); LOADW(cc + 1); }   // fly during compute
        __syncthreads();
#pragma unroll
        for (int ky = 0; ky < 3; ++ky) {
#pragma unroll
            for (int kx = 0; kx < 3; ++kx) {
                int tap = ky * 3 + kx;
                short8 a = sw8[(tap * 2 + h) * 64 + oc0 + ln];
#pragma unroll
                for (int nt = 0; nt < 4; ++nt) {
                    short8 bf = sx8[((wrow + ky) * 2 + h) * 132 + nt * 32 + ln + kx];
                    acc[nt] = __builtin_amdgcn_mfma_f32_32x32x16_bf16(a, bf, acc[nt], 0, 0, 0);
                }
            }
        }
    }

    int y = y0 + wrow;
    float* ob = out + (size_t)b * OC * HH * WW;
#pragma unroll
    for (int nt = 0; nt < 4; ++nt) {
#pragma unroll
        for (int r = 0; r < 16; ++r) {
            int oc = oc0 + (r & 3) + 8 * (r >> 2) + 4 * h;
            int px = nt * 32 + ln;
            ob[((size_t)oc * HH + y) * WW + px] = acc[nt][r] + s_bias[oc];
        }
    }
}

// ---------------------------------------------------------------------------
extern "C" void kernel_launch(void* const* d_in, const int* in_sizes, int n_in,
                              void* d_out, int out_size, void* d_ws, size_t ws_size,
                              hipStream_t stream) {
    const float* x      = (const float*)d_in[0];
    const float* w_addr = (const float*)d_in[1];
    const float* b_addr = (const float*)d_in[2];
    const float* w_bank = (const float*)d_in[3];
    const float* b_bank = (const float*)d_in[4];
    const float* aspace = (const float*)d_in[5];
    float* out = (float*)d_out;

    char* ws = (char*)d_ws;
    float*          sel_w = (float*)ws;                     // 32768 B
    float*          bias  = (float*)(ws + 32768);           //  8192 B
    __hip_bfloat16* wmb   = (__hip_bfloat16*)(ws + 40960);  // 2359296 B

    k_selw<<<BS, BANK, 0, stream>>>(w_addr, aspace, sel_w);
    k_bias<<<BS * OC, BANK, 0, stream>>>(b_addr, aspace, b_bank, bias);
    k_wmix<<<WELEM / 64, 256, 0, stream>>>(sel_w, w_bank, wmb);
    k_conv<<<BS * 32, 512, 0, stream>>>(x, wmb, bias, out);
}